// Round 6
// baseline (206.830 us; speedup 1.0000x reference)
//
#include <hip/hip_runtime.h>
#include <math.h>

#define N_ROWS   512     // 8*16*4
#define NBINS    257
#define KPAD     576     // padded K per window-half (18*32)
#define NCHUNKB  36      // B K-chunks total: 18 unshifted (h1) + 18 shifted (h2)
#define PCH      9       // A-chunks resident per phase
#define PCOLS    288     // A columns generated per phase
#define NOUT     256     // output samples per frame (STEP)
#define N_FRAMES 128
#define N_SAMP   32768
#define TWO_PI   6.283185307179586f
#define PADN     32      // fixed (zero-padded) nonzeros per items-column; E[nnz]=5.1
#define CSC_BLKS 13      // ceil(771/64)
#define N_COEFFS 771

typedef _Float16 half8 __attribute__((ext_vector_type(8)));
typedef float floatx4 __attribute__((ext_vector_type(4)));

// ============ Kernel 0: fused CSC build (blocks 0..12) + windowed basis =======
// Basis now folds the Hann window and OLA pairing INTO the fp16 B matrix:
//   chunks  0..17 : B'[k][n1] = hann(n1)     * trig(k, n1)       (h1 path)
//   chunks 18..35 : B''[k][n1] = hann(n1+256) * trig(k, n1+256)  (h2 path, A shifted)
// fragment-ready layout: element (kk, n1) at ((kk>>5)*4 + ((kk>>3)&3))*256*8 + n1*8 + (kk&7)
__global__ __launch_bounds__(256) void k_pre(const float* __restrict__ items,
                                             int* __restrict__ idx,
                                             float* __restrict__ val,
                                             _Float16* __restrict__ Bt) {
    const int bid = blockIdx.x;
    const int tid = threadIdx.x;
    if (bid >= CSC_BLKS) {
        int n1 = bid - CSC_BLKS;             // output column 0..255
        for (int kk = tid; kk < 2 * KPAD; kk += 256) {
            int half = kk >= KPAD;
            int k    = kk - half * KPAD;
            int s    = n1 + half * 256;      // window position / sample index
            float w  = 0.5f - 0.5f * cosf(TWO_PI * (float)s / 511.f);
            float v  = 0.f;
            if (k < NBINS) {
                int r = (k * s) & 511;
                v = cosf(TWO_PI * (float)r * (1.f / 512.f)) * w;
            } else if (k < 2 * NBINS) {
                int r = ((k - NBINS) * s) & 511;
                v = -sinf(TWO_PI * (float)r * (1.f / 512.f)) * w;
            }
            size_t pos = ((size_t)((kk >> 5) * 4 + ((kk >> 3) & 3)) * NOUT + n1) * 8 + (kk & 7);
            Bt[pos] = (_Float16)v;
        }
        return;
    }
    // ---- CSC: 64x64 tiles, global->reg (16 loads in flight) -> LDS -> ballot ----
    __shared__ float tile[64][65];
    __shared__ int   basec[64];
    const int c0   = bid * 64;
    const int w    = tid >> 6;
    const int lane = tid & 63;
    const int c    = c0 + lane;
    if (tid < 64) basec[tid] = 0;
    for (int r0 = 0; r0 < 512; r0 += 64) {
        float v[16];
        #pragma unroll
        for (int rr = 0; rr < 16; ++rr)
            v[rr] = (c < N_COEFFS) ? items[(size_t)(r0 + rr * 4 + w) * N_COEFFS + c] : 0.f;
        #pragma unroll
        for (int rr = 0; rr < 16; ++rr)
            tile[rr * 4 + w][lane] = v[rr];
        __syncthreads();
        #pragma unroll
        for (int cc = 0; cc < 16; ++cc) {
            int cl   = w * 16 + cc;
            int gcol = c0 + cl;
            float x  = tile[lane][cl];
            unsigned long long m = __ballot(x != 0.f);
            int base = basec[cl];
            int pos  = base + __popcll(m & ((1ull << lane) - 1ull));
            if (gcol < N_COEFFS && x != 0.f && pos < PADN) {
                idx[gcol * PADN + pos] = r0 + lane;
                val[gcol * PADN + pos] = x;
            }
            if (lane == 0) basec[cl] = base + __popcll(m);
        }
        __syncthreads();
    }
    for (int j = tid; j < 64 * PADN; j += 256) {
        int cl = j >> 5, pz = j & (PADN - 1);
        int gcol = c0 + cl;
        if (gcol < N_COEFFS) {
            int b = basec[cl]; b = b < PADN ? b : PADN;
            if (pz >= b) {
                idx[gcol * PADN + pz] = 0;
                val[gcol * PADN + pz] = 0.f;
            }
        }
    }
}

// ============ Kernel 1: fully fused params + A-gen + MFMA(K=1152) + norm ======
// One block per row, 512 threads (8 waves = 2 wm x 4 wn), wave owns 64f x 64n.
// Window/OLA folded into B => acc[4][4] (64 regs), no OLA epilogue, no Bsm,
// no permutation. Shifted half reads A[f-1] from the same Asm (f=0 -> zero).
// LDS ~78 KB => 2 blocks/CU possible; B direct from global (L2-resident).
__global__ __launch_bounds__(512, 3) void k_row(const float* __restrict__ sel,
                                                const int* __restrict__ csc_idx,
                                                const float* __restrict__ csc_val,
                                                const _Float16* __restrict__ basis,
                                                float* __restrict__ out) {
    __shared__ _Float16 Asm[PCH * 4096];   // 73728 B: 9 chunks x [f 128][32 swizzled]
    __shared__ float    par[NBINS * 4];    // 4112 B: {cos, sin, mag, D0} per bin
    __shared__ float    red[8];

    const int row  = blockIdx.x;
    const int t    = threadIdx.x;
    const int lane = t & 63;
    const int w    = t >> 6;
    const int wm   = w >> 2;            // frame-half 0..1 (64 frames each)
    const int wn   = w & 3;             // col-group 0..3 (64 output cols each)
    const int quad = lane >> 4;
    const int l16  = lane & 15;

    // ---------- fused params: relu(sel) -> LDS, sparse dots, transcendentals ----
    {
        float* s = (float*)Asm;         // scratch overlay, freed before agen(0)
        float v0 = sel[row * 512 + t];
        s[t] = v0 > 0.f ? v0 : 0.f;
        __syncthreads();
        if (t < NBINS) {
            float acc3[3];
            #pragma unroll
            for (int ch = 0; ch < 3; ++ch) {
                int cc = ch * NBINS + t;
                const int*   ip = csc_idx + cc * PADN;
                const float* vp = csc_val + cc * PADN;
                float a = 0.f;
                #pragma unroll
                for (int j = 0; j < PADN; ++j)
                    a = fmaf(s[ip[j]], vp[j], a);
                acc3[ch] = a;
            }
            float sig_m = 1.f / (1.f + expf(-acc3[0]));
            float mag   = 0.5f + sig_m * 0.9999f * 0.5f;
            float ph    = tanhf(acc3[1]) * 3.14159265358979323846f;
            float sph, cph;
            sincosf(ph, &sph, &cph);
            float st  = 1.f / (1.f + expf(-acc3[2]));
            float wgt = (t == 0 || t == 256) ? (1.f / 512.f) : (2.f / 512.f);
            float qx  = st * wgt;
            par[t * 4 + 0] = cph;
            par[t * 4 + 1] = sph;
            par[t * 4 + 2] = mag;
            par[t * 4 + 3] = 512.f * qx * mag;   // D0, identical arithmetic to R5
        }
        __syncthreads();
    }

    // ---------- A generation into Asm for one K-phase ----------
    auto agen = [&](int ph) {
        if (t < PCOLS) {
            int gc = ph * PCOLS + t;
            int bin; bool isCos;
            if (gc < NBINS)          { bin = gc;          isCos = true;  }
            else if (gc < 2 * NBINS) { bin = gc - NBINS;  isCos = false; }
            else                     { bin = 0;           isCos = true;  }
            float cph = par[bin * 4 + 0];
            float sph = par[bin * 4 + 1];
            float mag = par[bin * 4 + 2];
            float D   = par[bin * 4 + 3];
            if (gc >= 2 * NBINS) D = 0.f;
            float c = cph, s = sph;
            int ch = t >> 5, g = (t >> 3) & 3, o = t & 7;
            _Float16* base = &Asm[ch * 4096 + o];
            for (int f = 0; f < N_FRAMES; ++f) {
                float val = isCos ? D * c : D * s;
                base[f * 32 + ((g ^ ((f >> 1) & 3) ^ ((f >> 3) & 3)) << 3)] = (_Float16)val;
                D *= mag;
                float nc = fmaf(c, cph, -s * sph);
                float ns = fmaf(s, cph,  c * sph);
                c = nc; s = ns;
            }
        }
    };

    // B fragment base: element (chunk cb, plane quad, col u) at (cb*4+quad)*256*8 + u*8
    const _Float16* bbase = basis + ((size_t)quad * NOUT + wn * 64 + l16) * 8;

    floatx4 acc[4][4] = {};   // [mt][nt]
    const half8 hz = {};

    for (int ph = 0; ph < 2; ++ph) {
        if (ph == 0) { agen(0); }
        else         { __syncthreads(); agen(1); }
        __syncthreads();
        for (int ks = 0; ks < PCH; ++ks) {
            const int cb0 = ph * PCH + ks;        // unshifted (h1) chunk
            const int cb1 = cb0 + 18;             // shifted (h2) chunk
            half8 av[4], avs[4];
            #pragma unroll
            for (int mt = 0; mt < 4; ++mt) {
                int m  = wm * 64 + mt * 16 + l16;
                av[mt] = *(const half8*)&Asm[ks * 4096 + m * 32 +
                          ((quad ^ ((m >> 1) & 3) ^ ((m >> 3) & 3)) << 3)];
                int ms = m - 1; if (ms < 0) ms = 0;
                avs[mt] = *(const half8*)&Asm[ks * 4096 + ms * 32 +
                          ((quad ^ ((ms >> 1) & 3) ^ ((ms >> 3) & 3)) << 3)];
            }
            if (wm == 0 && l16 == 0) avs[0] = hz;   // frame -1 contributes zero
            #pragma unroll
            for (int nt = 0; nt < 4; ++nt) {
                half8 bv  = *(const half8*)(bbase + (size_t)cb0 * 8192 + nt * 128);
                half8 bvs = *(const half8*)(bbase + (size_t)cb1 * 8192 + nt * 128);
                #pragma unroll
                for (int mt = 0; mt < 4; ++mt)
                    acc[mt][nt] = __builtin_amdgcn_mfma_f32_16x16x32_f16(av[mt],  bv,  acc[mt][nt], 0, 0, 0);
                #pragma unroll
                for (int mt = 0; mt < 4; ++mt)
                    acc[mt][nt] = __builtin_amdgcn_mfma_f32_16x16x32_f16(avs[mt], bvs, acc[mt][nt], 0, 0, 0);
            }
        }
    }

    // ---------- epilogue: sum-of-squares, scale, store (no OLA needed) ----------
    float ssq = 0.f;
    #pragma unroll
    for (int mt = 0; mt < 4; ++mt)
        #pragma unroll
        for (int nt = 0; nt < 4; ++nt)
            #pragma unroll
            for (int rr = 0; rr < 4; ++rr)
                ssq = fmaf(acc[mt][nt][rr], acc[mt][nt][rr], ssq);
    #pragma unroll
    for (int off = 32; off > 0; off >>= 1) ssq += __shfl_down(ssq, off, 64);
    if (lane == 0) red[w] = ssq;
    __syncthreads();
    float tot = red[0] + red[1] + red[2] + red[3] + red[4] + red[5] + red[6] + red[7];
    float scale = 1.f / (sqrtf(tot) + 1e-8f);

    float* orow = out + (size_t)row * N_SAMP;
    #pragma unroll
    for (int mt = 0; mt < 4; ++mt) {
        #pragma unroll
        for (int nt = 0; nt < 4; ++nt) {
            int n1 = wn * 64 + nt * 16 + l16;
            #pragma unroll
            for (int rr = 0; rr < 4; ++rr) {
                int f = wm * 64 + mt * 16 + quad * 4 + rr;
                orow[f * 256 + n1] = acc[mt][nt][rr] * scale;
            }
        }
    }
}

extern "C" void kernel_launch(void* const* d_in, const int* in_sizes, int n_in,
                              void* d_out, int out_size, void* d_ws, size_t ws_size,
                              hipStream_t stream) {
    const float* sel   = (const float*)d_in[0];   // (8,16,4,512)
    const float* items = (const float*)d_in[1];   // (512,771)
    float* out = (float*)d_out;                   // (512, 32768)

    char* ws = (char*)d_ws;
    size_t off = 0;
    _Float16* basis = (_Float16*)(ws + off); off += (size_t)NCHUNKB * 4 * NOUT * 8 * 2; off = (off + 255) & ~255ull;
    int*   csc_idx = (int*)(ws + off);   off += (size_t)N_COEFFS * PADN * 4;  off = (off + 255) & ~255ull;
    float* csc_val = (float*)(ws + off); off += (size_t)N_COEFFS * PADN * 4;

    k_pre<<<dim3(CSC_BLKS + NOUT), dim3(256), 0, stream>>>(items, csc_idx, csc_val, basis);
    k_row<<<dim3(N_ROWS), dim3(512), 0, stream>>>(sel, csc_idx, csc_val, basis, out);
}

// Round 7
// 175.697 us; speedup vs baseline: 1.1772x; 1.1772x over previous
//
#include <hip/hip_runtime.h>
#include <math.h>

#define N_ROWS   512     // 8*16*4
#define NBINS    257
#define KPAD     576     // padded K per window-half (18*32)
#define NCHUNKB  36      // B K-chunks total: 18 unshifted (h1) + 18 shifted (h2)
#define PCH      9       // A-chunks resident per phase
#define PCOLS    288     // A columns generated per phase
#define NOUT     256     // output samples per frame (STEP)
#define N_FRAMES 128
#define N_SAMP   32768
#define TWO_PI   6.283185307179586f
#define PADN     32      // fixed (zero-padded) nonzeros per items-column; E[nnz]=5.1
#define CSC_BLKS 13      // ceil(771/64)
#define N_COEFFS 771

typedef _Float16 half8 __attribute__((ext_vector_type(8)));
typedef float floatx4 __attribute__((ext_vector_type(4)));

// ============ Kernel 0: fused CSC build (blocks 0..12) + windowed basis =======
// Basis folds the Hann window and OLA pairing INTO the fp16 B matrix:
//   chunks  0..17 : B'[k][n1] = hann(n1)      * trig(k, n1)      (h1 path)
//   chunks 18..35 : B''[k][n1] = hann(n1+256) * trig(k, n1+256)  (h2 path, A shifted)
// fragment-ready layout: element (kk, n1) at ((kk>>5)*4 + ((kk>>3)&3))*256*8 + n1*8 + (kk&7)
__global__ __launch_bounds__(256) void k_pre(const float* __restrict__ items,
                                             int* __restrict__ idx,
                                             float* __restrict__ val,
                                             _Float16* __restrict__ Bt) {
    const int bid = blockIdx.x;
    const int tid = threadIdx.x;
    if (bid >= CSC_BLKS) {
        int n1 = bid - CSC_BLKS;             // output column 0..255
        for (int kk = tid; kk < 2 * KPAD; kk += 256) {
            int half = kk >= KPAD;
            int k    = kk - half * KPAD;
            int s    = n1 + half * 256;      // window position / sample index
            float w  = 0.5f - 0.5f * cosf(TWO_PI * (float)s / 511.f);
            float v  = 0.f;
            if (k < NBINS) {
                int r = (k * s) & 511;
                v = cosf(TWO_PI * (float)r * (1.f / 512.f)) * w;
            } else if (k < 2 * NBINS) {
                int r = ((k - NBINS) * s) & 511;
                v = -sinf(TWO_PI * (float)r * (1.f / 512.f)) * w;
            }
            size_t pos = ((size_t)((kk >> 5) * 4 + ((kk >> 3) & 3)) * NOUT + n1) * 8 + (kk & 7);
            Bt[pos] = (_Float16)v;
        }
        return;
    }
    // ---- CSC: 64x64 tiles, global->reg (16 loads in flight) -> LDS -> ballot ----
    __shared__ float tile[64][65];
    __shared__ int   basec[64];
    const int c0   = bid * 64;
    const int w    = tid >> 6;
    const int lane = tid & 63;
    const int c    = c0 + lane;
    if (tid < 64) basec[tid] = 0;
    for (int r0 = 0; r0 < 512; r0 += 64) {
        float v[16];
        #pragma unroll
        for (int rr = 0; rr < 16; ++rr)
            v[rr] = (c < N_COEFFS) ? items[(size_t)(r0 + rr * 4 + w) * N_COEFFS + c] : 0.f;
        #pragma unroll
        for (int rr = 0; rr < 16; ++rr)
            tile[rr * 4 + w][lane] = v[rr];
        __syncthreads();
        #pragma unroll
        for (int cc = 0; cc < 16; ++cc) {
            int cl   = w * 16 + cc;
            int gcol = c0 + cl;
            float x  = tile[lane][cl];
            unsigned long long m = __ballot(x != 0.f);
            int base = basec[cl];
            int pos  = base + __popcll(m & ((1ull << lane) - 1ull));
            if (gcol < N_COEFFS && x != 0.f && pos < PADN) {
                idx[gcol * PADN + pos] = r0 + lane;
                val[gcol * PADN + pos] = x;
            }
            if (lane == 0) basec[cl] = base + __popcll(m);
        }
        __syncthreads();
    }
    for (int j = tid; j < 64 * PADN; j += 256) {
        int cl = j >> 5, pz = j & (PADN - 1);
        int gcol = c0 + cl;
        if (gcol < N_COEFFS) {
            int b = basec[cl]; b = b < PADN ? b : PADN;
            if (pz >= b) {
                idx[gcol * PADN + pz] = 0;
                val[gcol * PADN + pz] = 0.f;
            }
        }
    }
}

// ============ Kernel 1: fully fused params + A-gen + MFMA(K=2x576) + norm =====
// One block per row, 512 threads (8 waves = 2 wm x 4 wn), wave owns 64f x 64n.
// REGISTER BUDGET IS THE POINT: __launch_bounds__(512, 4) targets <=128 unified
// regs/thread (64 AGPR acc + <=64 arch) -> 4 waves/SIMD -> 2 blocks/CU resident
// (LDS 78336 B x 2 fits in 160 KB). The shifted-A pass REUSES av[] registers
// (two sequential passes per ks) instead of a second live avs[] set; this cuts
// 16 VGPRs and un-mixes the two LDS access patterns (bank conflicts).
__global__ __launch_bounds__(512, 4) void k_row(const float* __restrict__ sel,
                                                const int* __restrict__ csc_idx,
                                                const float* __restrict__ csc_val,
                                                const _Float16* __restrict__ basis,
                                                float* __restrict__ out) {
    __shared__ _Float16 Asm[PCH * 4096];   // 73728 B: 9 chunks x [f 128][32 swizzled]
    __shared__ float    par[NBINS * 4];    // 4112 B: {cos, sin, mag, D0} per bin
    __shared__ float    red[8];

    const int row  = blockIdx.x;
    const int t    = threadIdx.x;
    const int lane = t & 63;
    const int w    = t >> 6;
    const int wm   = w >> 2;            // frame-half 0..1 (64 frames each)
    const int wn   = w & 3;             // col-group 0..3 (64 output cols each)
    const int quad = lane >> 4;
    const int l16  = lane & 15;

    // ---------- fused params: relu(sel) -> LDS, sparse dots, transcendentals ----
    {
        float* s = (float*)Asm;         // scratch overlay, freed before agen(0)
        float v0 = sel[row * 512 + t];
        s[t] = v0 > 0.f ? v0 : 0.f;
        __syncthreads();
        if (t < NBINS) {
            float acc3[3];
            #pragma unroll
            for (int ch = 0; ch < 3; ++ch) {
                int cc = ch * NBINS + t;
                const int*   ip = csc_idx + cc * PADN;
                const float* vp = csc_val + cc * PADN;
                float a = 0.f;
                #pragma unroll
                for (int j = 0; j < PADN; ++j)
                    a = fmaf(s[ip[j]], vp[j], a);
                acc3[ch] = a;
            }
            float sig_m = 1.f / (1.f + expf(-acc3[0]));
            float mag   = 0.5f + sig_m * 0.9999f * 0.5f;
            float ph    = tanhf(acc3[1]) * 3.14159265358979323846f;
            float sph, cph;
            sincosf(ph, &sph, &cph);
            float st  = 1.f / (1.f + expf(-acc3[2]));
            float wgt = (t == 0 || t == 256) ? (1.f / 512.f) : (2.f / 512.f);
            float qx  = st * wgt;
            par[t * 4 + 0] = cph;
            par[t * 4 + 1] = sph;
            par[t * 4 + 2] = mag;
            par[t * 4 + 3] = 512.f * qx * mag;   // D0
        }
        __syncthreads();
    }

    // ---------- A generation into Asm for one K-phase ----------
    auto agen = [&](int ph) {
        if (t < PCOLS) {
            int gc = ph * PCOLS + t;
            int bin; bool isCos;
            if (gc < NBINS)          { bin = gc;          isCos = true;  }
            else if (gc < 2 * NBINS) { bin = gc - NBINS;  isCos = false; }
            else                     { bin = 0;           isCos = true;  }
            float cph = par[bin * 4 + 0];
            float sph = par[bin * 4 + 1];
            float mag = par[bin * 4 + 2];
            float D   = par[bin * 4 + 3];
            if (gc >= 2 * NBINS) D = 0.f;
            float c = cph, s = sph;
            int ch = t >> 5, g = (t >> 3) & 3, o = t & 7;
            _Float16* base = &Asm[ch * 4096 + o];
            for (int f = 0; f < N_FRAMES; ++f) {
                float val = isCos ? D * c : D * s;
                base[f * 32 + ((g ^ ((f >> 1) & 3) ^ ((f >> 3) & 3)) << 3)] = (_Float16)val;
                D *= mag;
                float nc = fmaf(c, cph, -s * sph);
                float ns = fmaf(s, cph,  c * sph);
                c = nc; s = ns;
            }
        }
    };

    // B fragment base: element (chunk cb, plane quad, col u) at (cb*4+quad)*256*8 + u*8
    const _Float16* bbase = basis + ((size_t)quad * NOUT + wn * 64 + l16) * 8;

    floatx4 acc[4][4] = {};   // [mt][nt] — 64 AGPRs
    const half8 hz = {};

    for (int ph = 0; ph < 2; ++ph) {
        if (ph == 0) { agen(0); }
        else         { __syncthreads(); agen(1); }
        __syncthreads();
        for (int ks = 0; ks < PCH; ++ks) {
            const int cb0 = ph * PCH + ks;        // unshifted (h1) chunk
            const int cb1 = cb0 + 18;             // shifted (h2) chunk
            // ---- pass 1: unshifted A x B' ----
            {
                half8 av[4];
                #pragma unroll
                for (int mt = 0; mt < 4; ++mt) {
                    int m = wm * 64 + mt * 16 + l16;
                    av[mt] = *(const half8*)&Asm[ks * 4096 + m * 32 +
                              ((quad ^ ((m >> 1) & 3) ^ ((m >> 3) & 3)) << 3)];
                }
                #pragma unroll
                for (int nt = 0; nt < 4; ++nt) {
                    half8 bv = *(const half8*)(bbase + (size_t)cb0 * 8192 + nt * 128);
                    #pragma unroll
                    for (int mt = 0; mt < 4; ++mt)
                        acc[mt][nt] = __builtin_amdgcn_mfma_f32_16x16x32_f16(av[mt], bv, acc[mt][nt], 0, 0, 0);
                }
            }
            // ---- pass 2: frame-shifted A x B'' (reuses av registers) ----
            {
                half8 av[4];
                #pragma unroll
                for (int mt = 0; mt < 4; ++mt) {
                    int m  = wm * 64 + mt * 16 + l16;
                    int ms = m - 1; if (ms < 0) ms = 0;
                    av[mt] = *(const half8*)&Asm[ks * 4096 + ms * 32 +
                              ((quad ^ ((ms >> 1) & 3) ^ ((ms >> 3) & 3)) << 3)];
                }
                if (wm == 0 && l16 == 0) av[0] = hz;   // frame -1 contributes zero
                #pragma unroll
                for (int nt = 0; nt < 4; ++nt) {
                    half8 bv = *(const half8*)(bbase + (size_t)cb1 * 8192 + nt * 128);
                    #pragma unroll
                    for (int mt = 0; mt < 4; ++mt)
                        acc[mt][nt] = __builtin_amdgcn_mfma_f32_16x16x32_f16(av[mt], bv, acc[mt][nt], 0, 0, 0);
                }
            }
        }
    }

    // ---------- epilogue: sum-of-squares, scale, store (no OLA needed) ----------
    float ssq = 0.f;
    #pragma unroll
    for (int mt = 0; mt < 4; ++mt)
        #pragma unroll
        for (int nt = 0; nt < 4; ++nt)
            #pragma unroll
            for (int rr = 0; rr < 4; ++rr)
                ssq = fmaf(acc[mt][nt][rr], acc[mt][nt][rr], ssq);
    #pragma unroll
    for (int off = 32; off > 0; off >>= 1) ssq += __shfl_down(ssq, off, 64);
    if (lane == 0) red[w] = ssq;
    __syncthreads();
    float tot = red[0] + red[1] + red[2] + red[3] + red[4] + red[5] + red[6] + red[7];
    float scale = 1.f / (sqrtf(tot) + 1e-8f);

    float* orow = out + (size_t)row * N_SAMP;
    #pragma unroll
    for (int mt = 0; mt < 4; ++mt) {
        #pragma unroll
        for (int nt = 0; nt < 4; ++nt) {
            int n1 = wn * 64 + nt * 16 + l16;
            #pragma unroll
            for (int rr = 0; rr < 4; ++rr) {
                int f = wm * 64 + mt * 16 + quad * 4 + rr;
                orow[f * 256 + n1] = acc[mt][nt][rr] * scale;
            }
        }
    }
}

extern "C" void kernel_launch(void* const* d_in, const int* in_sizes, int n_in,
                              void* d_out, int out_size, void* d_ws, size_t ws_size,
                              hipStream_t stream) {
    const float* sel   = (const float*)d_in[0];   // (8,16,4,512)
    const float* items = (const float*)d_in[1];   // (512,771)
    float* out = (float*)d_out;                   // (512, 32768)

    char* ws = (char*)d_ws;
    size_t off = 0;
    _Float16* basis = (_Float16*)(ws + off); off += (size_t)NCHUNKB * 4 * NOUT * 8 * 2; off = (off + 255) & ~255ull;
    int*   csc_idx = (int*)(ws + off);   off += (size_t)N_COEFFS * PADN * 4;  off = (off + 255) & ~255ull;
    float* csc_val = (float*)(ws + off); off += (size_t)N_COEFFS * PADN * 4;

    k_pre<<<dim3(CSC_BLKS + NOUT), dim3(256), 0, stream>>>(items, csc_idx, csc_val, basis);
    k_row<<<dim3(N_ROWS), dim3(512), 0, stream>>>(sel, csc_idx, csc_val, basis, out);
}